// Round 5
// baseline (87.446 us; speedup 1.0000x reference)
//
#include <hip/hip_runtime.h>

#define NB 32
#define TT 512
#define UU 100
#define UM 101   // U+1
#define VV 4096
#define NEG (-1e30f)
#define PD 24
#define DMAX 672
#define L2E 1.4426950408889634f
#define LN2 0.6931471805599453f

__device__ __forceinline__ float vexp2(float x){ float r; asm("v_exp_f32 %0, %1" : "=v"(r) : "v"(x)); return r; }
__device__ __forceinline__ float vlog2(float x){ float r; asm("v_log_f32 %0, %1" : "=v"(r) : "v"(x)); return r; }

// logaddexp in log2 domain; min-max form keeps the chain short
__device__ __forceinline__ float lae2(float a, float b) {
    float m  = fmaxf(a, b);
    float nd = fminf(a, b) - m;          // = -|a-b|
    return m + vlog2(1.0f + vexp2(nd));
}

// prep: blk[n][t] = enc[n][t][0]*L2E ; bdv[n][u<128] = dec[n][u][0]*L2E (0 pad) ;
//       dvx[n][j] = dec[n][j][y[n][j]]*L2E
__global__ void prep_k(const float* __restrict__ enc, const float* __restrict__ dec,
                       const int* __restrict__ tgt,
                       float* __restrict__ blk, float* __restrict__ bdv,
                       float* __restrict__ dvx) {
    int n = blockIdx.x, tid = threadIdx.x;   // 512 threads
    blk[n * TT + tid] = enc[((size_t)n * TT + tid) * VV] * L2E;
    if (tid < 128)
        bdv[n * 128 + tid] = (tid < UM) ? dec[((size_t)n * UM + tid) * VV] * L2E : 0.0f;
    if (tid < UU) {
        int y = tgt[n * UU + tid];
        dvx[n * UU + tid] = dec[((size_t)n * UM + tid) * VV + y] * L2E;
    }
}

// diagonal-major emit stream, coalesced float2 writes.
// st[n][d][lane] = {e(u=2L), e(u=2L+1)}, t = d - u, already *L2E with dec part added.
__global__ void build_k(const float* __restrict__ enc, const int* __restrict__ tgt,
                        const int* __restrict__ ilen, const int* __restrict__ tlen,
                        const float* __restrict__ dvx, float2* __restrict__ st) {
    int n = blockIdx.y;
    int d = blockIdx.x * 4 + (threadIdx.x >> 6);
    int lane = threadIdx.x & 63;
    int tin = ilen[n], tg = tlen[n];
    const float* encn = enc + (size_t)n * TT * VV;
    float e0 = NEG, e1 = NEG;
    {   // slot 0: u = 2*lane
        int u = 2 * lane, t = d - u;
        if (u >= 1 && u <= tg && t >= 0 && t < tin)
            e0 = fmaf(encn[(size_t)t * VV + tgt[n * UU + u - 1]], L2E, dvx[n * UU + u - 1]);
    }
    {   // slot 1: u = 2*lane + 1
        int u = 2 * lane + 1, t = d - u;
        if (u <= tg && t >= 0 && t < tin)
            e1 = fmaf(encn[(size_t)t * VV + tgt[n * UU + u - 1]], L2E, dvx[n * UU + u - 1]);
    }
    st[((size_t)n * DMAX + d) * 64 + lane] = make_float2(e0, e1);
}

// wavefront DP: lane L owns u=2L (a0) and u=2L+1 (a1).
// blank edges rebuilt from NEG-padded LDS blk (no guards needed); emit from float2
// stream. Register rings of depth PD, pinned with sched_barrier(0).
__global__ __launch_bounds__(64, 1) void dp_k(const int* __restrict__ ilen,
                                              const int* __restrict__ tlen,
                                              const float2* __restrict__ st,
                                              const float* __restrict__ blk,
                                              const float* __restrict__ bdv,
                                              float* __restrict__ out) {
    int n = blockIdx.x;
    int lane = threadIdx.x;
    int tin = ilen[n], tg = tlen[n];
    int dend = tin - 1 + tg;

    // blkL[128 + t] = blk[n][t]; NEG pads cover t-1 outside [0,TT) — no range guards
    __shared__ float blkL[864];
    for (int i = lane; i < 864; i += 64) blkL[i] = NEG;
    __syncthreads();
    for (int t = lane; t < TT; t += 64) blkL[128 + t] = blk[n * TT + t];
    __syncthreads();

    float bd0 = bdv[n * 128 + 2 * lane];
    float bd1 = bdv[n * 128 + 2 * lane + 1];
    const float2* sp = st + ((size_t)n * DMAX) * 64 + lane;
    int ib = 126 - 2 * lane;   // blkL index of slot1's blk[t-1] is ib + d
    bool cap0 = (2 * lane == tg), cap1 = (2 * lane + 1 == tg);
    bool fx16 = (lane == 16), fx32 = (lane == 32), fx48 = (lane == 48);

    float a0 = (lane == 0) ? 0.0f : NEG;   // alpha[0][0] = 0 at d=0
    float a1 = NEG;
    float res = NEG;

    float Ae0[PD], Ae1[PD], Ab0[PD], Ab1[PD];
    float Be0[PD], Be1[PD], Bb0[PD], Bb1[PD];

#define LOADR(E0, E1, B0, B1, K, DD)                                   \
    {                                                                   \
        int dc = min((DD), DMAX - 1);                                   \
        float2 ev = sp[(size_t)dc * 64];                                \
        float b1s = blkL[ib + dc];                                      \
        float b0s = blkL[ib + dc + 1];                                  \
        E0[K] = ev.x; E1[K] = ev.y;                                     \
        B0[K] = b0s + bd0; B1[K] = b1s + bd1;                           \
    }

    auto STEP = [&](float e0, float e1, float bb0, float bb1, int dd) {
        // left neighbor of u=2L is lane L-1's a1: DPP row_shr:1 + row-seam fixups
        int sh = __builtin_amdgcn_update_dpp(__float_as_int(NEG), __float_as_int(a1),
                                             0x111, 0xF, 0xF, false);   // row_shr:1
        float s15 = __int_as_float(__builtin_amdgcn_readlane(__float_as_int(a1), 15));
        float s31 = __int_as_float(__builtin_amdgcn_readlane(__float_as_int(a1), 31));
        float s47 = __int_as_float(__builtin_amdgcn_readlane(__float_as_int(a1), 47));
        float l0 = __int_as_float(sh);
        l0 = fx16 ? s15 : l0;
        l0 = fx32 ? s31 : l0;
        l0 = fx48 ? s47 : l0;
        float bt0 = a0 + bb0, et0 = l0 + e0;
        float bt1 = a1 + bb1, et1 = a0 + e1;   // u=2L+1's left neighbor: same-lane old a0
        a0 = lae2(bt0, et0);
        a1 = lae2(bt1, et1);
        if (dd == dend) { if (cap0) res = a0; if (cap1) res = a1; }
    };

#pragma unroll
    for (int k = 0; k < PD; ++k) LOADR(Ae0, Ae1, Ab0, Ab1, k, 1 + k);
    __builtin_amdgcn_sched_barrier(0);

    for (int d = 1; d <= dend; d += 2 * PD) {
#pragma unroll
        for (int k = 0; k < PD; ++k) LOADR(Be0, Be1, Bb0, Bb1, k, d + PD + k);
        __builtin_amdgcn_sched_barrier(0);
#pragma unroll
        for (int k = 0; k < PD; ++k) STEP(Ae0[k], Ae1[k], Ab0[k], Ab1[k], d + k);
        __builtin_amdgcn_sched_barrier(0);
#pragma unroll
        for (int k = 0; k < PD; ++k) LOADR(Ae0, Ae1, Ab0, Ab1, k, d + 2 * PD + k);
        __builtin_amdgcn_sched_barrier(0);
#pragma unroll
        for (int k = 0; k < PD; ++k) STEP(Be0[k], Be1[k], Bb0[k], Bb1[k], d + PD + k);
        __builtin_amdgcn_sched_barrier(0);
    }

    float fin  = blkL[128 + tin - 1];
    float bdtg = bdv[n * 128 + tg];
    if (cap0 | cap1) out[n] = (res + fin + bdtg) * LN2;
#undef LOADR
}

extern "C" void kernel_launch(void* const* d_in, const int* in_sizes, int n_in,
                              void* d_out, int out_size, void* d_ws, size_t ws_size,
                              hipStream_t hs) {
    const float* enc  = (const float*)d_in[0];
    const float* dec  = (const float*)d_in[1];
    const int*   tgt  = (const int*)d_in[2];
    const int*   ilen = (const int*)d_in[3];
    const int*   tlen = (const int*)d_in[4];
    float* out = (float*)d_out;

    float2* st  = (float2*)d_ws;                          // 11 MB
    float*  blk = (float*)(st + (size_t)NB * DMAX * 64);  // 64 KB
    float*  bdv = blk + NB * TT;                          // 16 KB
    float*  dvx = bdv + NB * 128;                         // 12.8 KB

    hipLaunchKernelGGL(prep_k,  dim3(NB), dim3(512), 0, hs, enc, dec, tgt, blk, bdv, dvx);
    hipLaunchKernelGGL(build_k, dim3(DMAX / 4, NB), dim3(256), 0, hs,
                       enc, tgt, ilen, tlen, dvx, st);
    hipLaunchKernelGGL(dp_k,    dim3(NB), dim3(64), 0, hs, ilen, tlen, st, blk, bdv, out);
}

// Round 6
// 71.897 us; speedup vs baseline: 1.2163x; 1.2163x over previous
//
#include <hip/hip_runtime.h>

#define NB 32
#define TT 512
#define UU 100
#define UM 101   // U+1
#define VV 4096
#define NEG (-1e30f)
#define WIN 64
#define L2E 1.4426950408889634f
#define LN2 0.6931471805599453f

__device__ __forceinline__ float vexp2(float x){ float r; asm("v_exp_f32 %0, %1" : "=v"(r) : "v"(x)); return r; }
__device__ __forceinline__ float vlog2(float x){ float r; asm("v_log_f32 %0, %1" : "=v"(r) : "v"(x)); return r; }

// logaddexp in log2 domain
__device__ __forceinline__ float lae2(float a, float b) {
    float m  = fmaxf(a, b);
    float nd = fminf(a, b) - m;          // = -|a-b|
    return m + vlog2(1.0f + vexp2(nd));
}

// One block per batch element n. Wave 0 = DP consumer; waves 1..15 = producers
// gathering emit values for the NEXT 64-diagonal window into a double-buffered
// LDS ring. Barrier per window. Lane L of wave 0 owns u=2L (a0) and u=2L+1 (a1).
__global__ __launch_bounds__(1024, 1) void fused_k(
        const float* __restrict__ enc, const float* __restrict__ dec,
        const int* __restrict__ tgt, const int* __restrict__ ilen,
        const int* __restrict__ tlen, float* __restrict__ out) {
    __shared__ float em[2][WIN][128];   // em[w][dm][u] : emit edge into (t=d-u, u), d = base+dm+1
    __shared__ float blkL[864];         // blkL[128+t] = enc[n][t][0]*L2E, NEG-padded
    __shared__ int   tgtL[UU];
    __shared__ float dvxL[UU];          // dec[n][j][y_j]*L2E

    int n = blockIdx.x;
    int tid = threadIdx.x;
    int tin = ilen[n], tg = tlen[n];
    int dend = tin - 1 + tg;
    int E = (dend + WIN - 1) / WIN;     // epochs, uniform within block
    const float* encn = enc + (size_t)n * TT * VV;

    // ---- stage small tables (all threads) ----
    for (int i = tid; i < 864; i += 1024)
        blkL[i] = (i >= 128 && i < 128 + TT) ? encn[(size_t)(i - 128) * VV] * L2E : NEG;
    if (tid < UU) {
        int y = tgt[n * UU + tid];
        tgtL[tid] = y;
        dvxL[tid] = dec[((size_t)n * UM + tid) * VV + y] * L2E;
    }
    __syncthreads();

    int wave = tid >> 6;
    int lane = tid & 63;

    // producer: fill window w for diagonals d = baseDp+1 .. baseDp+WIN
    auto FILLWIN = [&](int w, int baseDp) {
        int pid = tid - 64;             // 0..959
        float* emw = &em[w][0][0];
#pragma unroll
        for (int it = 0; it < 9; ++it) {
            int idx = pid + it * 960;
            if (idx < WIN * 128) {
                int dm = idx >> 7, u = idx & 127;
                int d = baseDp + dm + 1;
                int t = d - u;
                float val = NEG;
                if (u >= 1 && u <= tg && t >= 0 && t < tin)
                    val = fmaf(encn[(size_t)t * VV + tgtL[u - 1]], L2E, dvxL[u - 1]);
                emw[idx] = val;
            }
        }
    };

    if (wave != 0) FILLWIN(0, 0);       // prefill window 0 (consumer preps meanwhile)

    // ---- consumer state (wave 0; harmless elsewhere) ----
    int u0c = min(2 * lane, UM - 1), u1c = min(2 * lane + 1, UM - 1);
    float bd0 = dec[((size_t)n * UM + u0c) * VV] * L2E;   // dec[n][u][0]*L2E (clamped, junk-safe)
    float bd1 = dec[((size_t)n * UM + u1c) * VV] * L2E;
    int ib0 = 127 - 2 * lane;           // blkL idx of slot0's blk[t-1] is ib0 + d
    bool cap0 = (2 * lane == tg), cap1 = (2 * lane + 1 == tg);
    bool fx16 = (lane == 16), fx32 = (lane == 32), fx48 = (lane == 48);
    float a0 = (lane == 0) ? 0.0f : NEG;   // alpha[0][0] = 0 at d=0
    float a1 = NEG;
    float res = NEG;

    float Ae0[8], Ae1[8], Ab0[8], Ab1[8], Be0[8], Be1[8], Bb0[8], Bb1[8];

    auto REFILL = [&](float (&Re0)[8], float (&Re1)[8], float (&Rb0)[8], float (&Rb1)[8],
                      int j0, int dbase, const float* emb) {
#pragma unroll
        for (int k = 0; k < 8; ++k) {
            int dm = j0 + k;
            float2 ev = *(const float2*)(emb + dm * 128 + 2 * lane);
            int d = dbase + dm + 1;
            Re0[k] = ev.x; Re1[k] = ev.y;
            Rb0[k] = blkL[ib0 + d] + bd0;
            Rb1[k] = blkL[ib0 + d - 1] + bd1;
        }
        __builtin_amdgcn_sched_barrier(0);
    };

    auto STEPS = [&](float (&Re0)[8], float (&Re1)[8], float (&Rb0)[8], float (&Rb1)[8],
                     int j0, int dbase) {
#pragma unroll
        for (int k = 0; k < 8; ++k) {
            int dd = dbase + j0 + k + 1;
            // left neighbor of u=2L is lane L-1's a1: DPP row_shr:1 + row-seam fixups
            int sh = __builtin_amdgcn_update_dpp(__float_as_int(NEG), __float_as_int(a1),
                                                 0x111, 0xF, 0xF, false);   // row_shr:1
            float s15 = __int_as_float(__builtin_amdgcn_readlane(__float_as_int(a1), 15));
            float s31 = __int_as_float(__builtin_amdgcn_readlane(__float_as_int(a1), 31));
            float s47 = __int_as_float(__builtin_amdgcn_readlane(__float_as_int(a1), 47));
            float l0 = __int_as_float(sh);
            l0 = fx16 ? s15 : l0;
            l0 = fx32 ? s31 : l0;
            l0 = fx48 ? s47 : l0;
            float bt0 = a0 + Rb0[k], et0 = l0 + Re0[k];
            float bt1 = a1 + Rb1[k], et1 = a0 + Re1[k];   // old a0: same-lane left neighbor
            a0 = lae2(bt0, et0);
            a1 = lae2(bt1, et1);
            if (dd == dend) { if (cap0) res = a0; if (cap1) res = a1; }
        }
        __builtin_amdgcn_sched_barrier(0);
    };

    __syncthreads();                    // window 0 ready

    for (int e = 0; e < E; ++e) {
        if (wave == 0) {
            int dbase = e * WIN;
            const float* emb = &em[e & 1][0][0];
            REFILL(Ae0, Ae1, Ab0, Ab1, 0, dbase, emb);
            REFILL(Be0, Be1, Bb0, Bb1, 8, dbase, emb);  STEPS(Ae0, Ae1, Ab0, Ab1, 0, dbase);
            REFILL(Ae0, Ae1, Ab0, Ab1, 16, dbase, emb); STEPS(Be0, Be1, Bb0, Bb1, 8, dbase);
            REFILL(Be0, Be1, Bb0, Bb1, 24, dbase, emb); STEPS(Ae0, Ae1, Ab0, Ab1, 16, dbase);
            REFILL(Ae0, Ae1, Ab0, Ab1, 32, dbase, emb); STEPS(Be0, Be1, Bb0, Bb1, 24, dbase);
            REFILL(Be0, Be1, Bb0, Bb1, 40, dbase, emb); STEPS(Ae0, Ae1, Ab0, Ab1, 32, dbase);
            REFILL(Ae0, Ae1, Ab0, Ab1, 48, dbase, emb); STEPS(Be0, Be1, Bb0, Bb1, 40, dbase);
            REFILL(Be0, Be1, Bb0, Bb1, 56, dbase, emb); STEPS(Ae0, Ae1, Ab0, Ab1, 48, dbase);
            STEPS(Be0, Be1, Bb0, Bb1, 56, dbase);
        } else {
            FILLWIN((e + 1) & 1, (e + 1) * WIN);   // fill next window (unused junk if last)
        }
        __syncthreads();
    }

    if (wave == 0 && (cap0 | cap1)) {
        float fin  = blkL[128 + tin - 1];
        float bdtg = dec[((size_t)n * UM + tg) * VV] * L2E;
        out[n] = (res + fin + bdtg) * LN2;
    }
}

extern "C" void kernel_launch(void* const* d_in, const int* in_sizes, int n_in,
                              void* d_out, int out_size, void* d_ws, size_t ws_size,
                              hipStream_t hs) {
    const float* enc  = (const float*)d_in[0];
    const float* dec  = (const float*)d_in[1];
    const int*   tgt  = (const int*)d_in[2];
    const int*   ilen = (const int*)d_in[3];
    const int*   tlen = (const int*)d_in[4];
    float* out = (float*)d_out;

    hipLaunchKernelGGL(fused_k, dim3(NB), dim3(1024), 0, hs,
                       enc, dec, tgt, ilen, tlen, out);
}